// Round 1
// baseline (543.613 us; speedup 1.0000x reference)
//
#include <hip/hip_runtime.h>

#define N_NODES 16384
#define KDIM    16384
#define E_EDGES 524288
#define H1DIM   200
#define H2DIM   8
#define BNP     256     // padded H1

#define BM 64
#define BK 32
#define KSPLIT 4
#define KLEN 4096       // KDIM / KSPLIT
#define NT 128          // KLEN / BK

typedef __attribute__((ext_vector_type(8))) short bf16x8;
typedef __attribute__((ext_vector_type(4))) float fx4;
typedef __attribute__((ext_vector_type(4))) unsigned int ux4;

__device__ __forceinline__ unsigned short f2bf(float f) {
  unsigned int u = __builtin_bit_cast(unsigned int, f);
  return (unsigned short)((u + 0x7FFFu + ((u >> 16) & 1u)) >> 16);  // RNE
}
__device__ __forceinline__ unsigned int pk2(float a, float b) {
  return (unsigned int)f2bf(a) | ((unsigned int)f2bf(b) << 16);
}

// ---------------- degree / CSR build ----------------

__global__ void k_init(float* deg, int* cnt) {
  int i = blockIdx.x * 256 + threadIdx.x;
  if (i < N_NODES) { deg[i] = 1.0f; cnt[i] = 0; }   // self-loop weight 1.0
}

__global__ void k_degcnt(const int* __restrict__ ei, const float* __restrict__ ew,
                         float* deg, int* cnt) {
  int e = blockIdx.x * 256 + threadIdx.x;
  if (e < E_EDGES) {
    int c = ei[E_EDGES + e];
    atomicAdd(&deg[c], ew[e]);
    atomicAdd(&cnt[c], 1);
  }
}

__global__ void k_dinv(const float* __restrict__ deg, float* dinv) {
  int i = blockIdx.x * 256 + threadIdx.x;
  if (i < N_NODES) dinv[i] = rsqrtf(deg[i]);        // deg >= 1 always
}

__global__ void k_scan(const int* __restrict__ cnt, int* __restrict__ off,
                       int* __restrict__ cursor) {
  __shared__ int s[1024];
  int t = threadIdx.x;
  int base = t * 16;
  int loc[16]; int sum = 0;
#pragma unroll
  for (int i = 0; i < 16; ++i) { loc[i] = cnt[base + i]; sum += loc[i]; }
  s[t] = sum; __syncthreads();
  for (int d = 1; d < 1024; d <<= 1) {
    int v = (t >= d) ? s[t - d] : 0;
    __syncthreads();
    s[t] += v;
    __syncthreads();
  }
  int run = (t == 0) ? 0 : s[t - 1];
#pragma unroll
  for (int i = 0; i < 16; ++i) { off[base + i] = run; cursor[base + i] = run; run += loc[i]; }
  if (t == 1023) off[N_NODES] = run;
}

__global__ void k_scatter(const int* __restrict__ ei, const float* __restrict__ ew,
                          const float* __restrict__ dinv, int* cursor,
                          int* __restrict__ r2, float* __restrict__ w2) {
  int e = blockIdx.x * 256 + threadIdx.x;
  if (e < E_EDGES) {
    int r = ei[e], c = ei[E_EDGES + e];
    float w = dinv[r] * ew[e] * dinv[c];
    int p = atomicAdd(&cursor[c], 1);
    r2[p] = r; w2[p] = w;
  }
}

// ---------------- W1 pack: bf16, zero-pad to 256, [k/8][n][8] tiling ----------------

__global__ void k_packW1(const float* __restrict__ W1, unsigned short* __restrict__ Wt) {
  int idx = blockIdx.x * 256 + threadIdx.x;   // < 16384*256
  int n = idx & 255, k = idx >> 8;
  float v = (n < H1DIM) ? W1[(size_t)k * H1DIM + n] : 0.0f;
  Wt[(size_t)(k >> 3) * 2048 + n * 8 + (k & 7)] = f2bf(v);
}

// ---------------- GEMM1: h1p[ks] = x[:, kslice] @ W1pad  (bf16 MFMA) ----------------

__launch_bounds__(256, 3)
__global__ void k_gemm1(const float* __restrict__ x, const unsigned short* __restrict__ Wt,
                        float* __restrict__ h1p) {
  __shared__ char lds[40960];       // A: [2][4096] @0, B: [2][16384] @8192
  const int t = threadIdx.x;
  const int wv = t >> 6;
  const int ln = t & 63;
  const int g = ln >> 4, l15 = ln & 15;
  const size_t m0 = (size_t)blockIdx.x * BM;
  const int ks = blockIdx.y;
  const int k0 = ks * KLEN;

  // A staging coords: thread t -> (m = t/4, kblk = t%4)
  const int am = t >> 2;
  const int akblk = t & 3;
  const float* xp0 = x + (m0 + am) * (size_t)KDIM + k0 + akblk * 8;
  const unsigned short* wbase = Wt + (size_t)k0 * 256;

  char* ldsA = lds;
  char* ldsB = lds + 8192;

  fx4 acc[4][4] = {};
  fx4 a0, a1;

  auto stageB = [&](int buf, int kt) {
    const unsigned short* src = wbase + (size_t)kt * 8192 + (size_t)t * 8;
    char* dstbase = ldsB + buf * 16384 + wv * 1024;   // wave-uniform; +lane*16 implicit
#pragma unroll
    for (int i = 0; i < 4; ++i) {
      __builtin_amdgcn_global_load_lds(
          (const __attribute__((address_space(1))) void*)(src + i * 2048),
          (__attribute__((address_space(3))) void*)(dstbase + i * 4096),
          16, 0, 0);
    }
  };
  auto loadA = [&](int kt) {
    const float* p = xp0 + kt * BK;
    a0 = *(const fx4*)p;
    a1 = *(const fx4*)(p + 4);
  };
  auto writeA = [&](int buf) {
    ux4 d;
    d[0] = pk2(a0[0], a0[1]); d[1] = pk2(a0[2], a0[3]);
    d[2] = pk2(a1[0], a1[1]); d[3] = pk2(a1[2], a1[3]);
    *(ux4*)(ldsA + buf * 4096 + ((akblk * 64 + am) << 4)) = d;
  };
  auto compute = [&](int buf) {
    const char* pa = ldsA + buf * 4096;
    const char* pb = ldsB + buf * 16384;
    bf16x8 af[4], bfr[4];
#pragma unroll
    for (int mi = 0; mi < 4; ++mi)
      af[mi] = *(const bf16x8*)(pa + ((g * 64 + mi * 16 + l15) << 4));
#pragma unroll
    for (int ni = 0; ni < 4; ++ni)
      bfr[ni] = *(const bf16x8*)(pb + ((g * 256 + wv * 64 + ni * 16 + l15) << 4));
#pragma unroll
    for (int mi = 0; mi < 4; ++mi)
#pragma unroll
      for (int ni = 0; ni < 4; ++ni)
        acc[mi][ni] = __builtin_amdgcn_mfma_f32_16x16x32_bf16(af[mi], bfr[ni], acc[mi][ni], 0, 0, 0);
  };

  // prologue
  stageB(0, 0); loadA(0); writeA(0);
  __syncthreads();

  for (int kt = 0; kt < NT; ++kt) {
    const int cur = kt & 1, nxt = cur ^ 1;
    if (kt + 1 < NT) { stageB(nxt, kt + 1); loadA(kt + 1); }
    compute(cur);
    if (kt + 1 < NT) writeA(nxt);
    __syncthreads();
  }

  float* outp = h1p + (size_t)ks * ((size_t)N_NODES * BNP);
#pragma unroll
  for (int mi = 0; mi < 4; ++mi)
#pragma unroll
    for (int ni = 0; ni < 4; ++ni)
#pragma unroll
      for (int r = 0; r < 4; ++r)
        outp[(m0 + mi * 16 + g * 4 + r) * BNP + wv * 64 + ni * 16 + l15] = acc[mi][ni][r];
}

__global__ void k_reduce(float* __restrict__ h1p) {
  size_t i = (size_t)blockIdx.x * 256 + threadIdx.x;   // < 1048576 fx4
  fx4* a = (fx4*)h1p;
  fx4 v = a[i];
  v += a[i + 1048576]; v += a[i + 2097152]; v += a[i + 3145728];
  a[i] = v;
}

// ---------------- layer-1 aggregation + bias + relu ----------------

__global__ void k_agg1(const float* __restrict__ h1, const int* __restrict__ r2,
                       const float* __restrict__ w2, const int* __restrict__ off,
                       const float* __restrict__ dinv, const float* __restrict__ b1,
                       float* __restrict__ h1r) {
  int c = blockIdx.x;
  int j = threadIdx.x;          // 0..255; cols 200..255 of h1 are exactly zero
  int p0 = off[c], p1 = off[c + 1];
  float acc = 0.0f;
  for (int p = p0; p < p1; ++p) {
    int r = r2[p]; float w = w2[p];
    acc += w * h1[(size_t)r * BNP + j];
  }
  float d = dinv[c];
  acc += d * d * h1[(size_t)c * BNP + j];
  if (j < H1DIM) {
    acc += b1[j];
    h1r[(size_t)c * H1DIM + j] = fmaxf(acc, 0.0f);
  }
}

// ---------------- layer-2 linear ----------------

__global__ void k_gemm2(const float* __restrict__ h1r, const float* __restrict__ W2,
                        float* __restrict__ g) {
  __shared__ float w2s[H1DIM * H2DIM];
  int t = threadIdx.x;
  for (int i = t; i < H1DIM * H2DIM; i += 256) w2s[i] = W2[i];
  __syncthreads();
  int r = t >> 3, j = t & 7;
  size_t i = (size_t)blockIdx.x * 32 + r;
  const float* hrow = h1r + i * H1DIM;
  float acc = 0.0f;
#pragma unroll 8
  for (int k = 0; k < H1DIM; ++k) acc = fmaf(hrow[k], w2s[k * 8 + j], acc);
  g[i * 8 + j] = acc;
}

// ---------------- layer-2 aggregation + bias ----------------

__global__ void k_agg2(const float* __restrict__ g, const int* __restrict__ r2,
                       const float* __restrict__ w2, const int* __restrict__ off,
                       const float* __restrict__ dinv, const float* __restrict__ b2,
                       float* __restrict__ out) {
  int t = threadIdx.x;
  int c = blockIdx.x * 32 + (t >> 3), j = t & 7;
  int p0 = off[c], p1 = off[c + 1];
  float acc = 0.0f;
  for (int p = p0; p < p1; ++p) acc += w2[p] * g[(size_t)r2[p] * 8 + j];
  float d = dinv[c];
  out[(size_t)c * 8 + j] = acc + d * d * g[(size_t)c * 8 + j] + b2[j];
}

// ---------------- launch ----------------

extern "C" void kernel_launch(void* const* d_in, const int* in_sizes, int n_in,
                              void* d_out, int out_size, void* d_ws, size_t ws_size,
                              hipStream_t stream) {
  (void)in_sizes; (void)n_in; (void)out_size; (void)ws_size;
  const float* x  = (const float*)d_in[0];
  const int*   ei = (const int*)d_in[1];
  const float* ew = (const float*)d_in[2];
  const float* W1 = (const float*)d_in[3];
  const float* b1 = (const float*)d_in[4];
  const float* W2 = (const float*)d_in[5];
  const float* b2 = (const float*)d_in[6];
  float* out = (float*)d_out;
  char* ws = (char*)d_ws;

  float* deg    = (float*)(ws + 0);          // 64 KiB
  float* dinv   = (float*)(ws + 65536);      // 64 KiB
  int*   cnt    = (int*)  (ws + 131072);     // 64 KiB
  int*   off    = (int*)  (ws + 196608);     // 16385 ints
  int*   cursor = (int*)  (ws + 262400);     // 64 KiB
  int*   r2     = (int*)  (ws + 327936);     // 2 MiB
  float* w2     = (float*)(ws + 2425088);    // 2 MiB
  unsigned short* Wt = (unsigned short*)(ws + 4522240);   // 8 MiB bf16 packed
  float* h1p    = (float*)(ws + 12910848);   // 4 * [16384][256] f32 = 64 MiB
  float* h1r    = (float*)(ws + 80019712);   // [16384][200] f32
  float* g      = (float*)(ws + 93126912);   // [16384][8] f32

  k_init   <<<64,    256, 0, stream>>>(deg, cnt);
  k_degcnt <<<2048,  256, 0, stream>>>(ei, ew, deg, cnt);
  k_dinv   <<<64,    256, 0, stream>>>(deg, dinv);
  k_scan   <<<1,    1024, 0, stream>>>(cnt, off, cursor);
  k_scatter<<<2048,  256, 0, stream>>>(ei, ew, dinv, cursor, r2, w2);
  k_packW1 <<<16384, 256, 0, stream>>>(W1, Wt);
  k_gemm1  <<<dim3(256, KSPLIT), 256, 0, stream>>>(x, Wt, h1p);
  k_reduce <<<4096,  256, 0, stream>>>(h1p);
  k_agg1   <<<16384, 256, 0, stream>>>(h1p, r2, w2, off, dinv, b1, h1r);
  k_gemm2  <<<512,   256, 0, stream>>>(h1r, W2, g);
  k_agg2   <<<512,   256, 0, stream>>>(g, r2, w2, off, dinv, b2, out);
}